// Round 8
// baseline (12990.042 us; speedup 1.0000x reference)
//
#include <hip/hip_runtime.h>

typedef __attribute__((ext_vector_type(8))) short short8;
typedef __attribute__((ext_vector_type(4))) float f32x4;

#define MFMA(a,b,c) __builtin_amdgcn_mfma_f32_16x16x32_bf16(a,b,c,0,0,0)

// Problem dims
#define S_LEN 128
#define IN_D  8
#define HID   512
#define NL    3
#define HSTR  536       // bf16 h row stride (shorts)

// ws layout (bytes)
#define OFF_WHH  0                       // [3][32][16][3][64][8] bf16 = 4,718,592
#define OFF_WIH  (4718592)               // [3][32][3][64][8] bf16    =   294,912
#define OFF_FLAG (4718592 + 294912)      // 256 * int                 =     1,024
#define OFF_XCHG (OFF_FLAG + 1024)       // 256 blk * 2 slot * 16 KB  = 8,388,608

__device__ __forceinline__ unsigned short f2bf(float f){
  unsigned u = __float_as_uint(f);
  u += 0x7FFFu + ((u >> 16) & 1u);     // round-to-nearest-even
  return (unsigned short)(u >> 16);
}

// Pack Whh [3][1536][512] f32 -> bf16 B-fragments, gate-interleaved per kk:
// dst chunk gid = (((l*32+nt)*16+kk)*3+g)*64+lane ; holds Whh[l][g*512+nt*16+(lane&15)][kk*32+(lane>>4)*8+j]
__global__ void prep_whh(const float* __restrict__ Whh, unsigned short* __restrict__ Wp){
  int gid = blockIdx.x * 256 + threadIdx.x;     // 294912 total
  int lane = gid & 63;
  int r = gid >> 6;
  int g  = r % 3;  r /= 3;
  int kk = r & 15; r >>= 4;
  int nt = r & 31;
  int l  = r >> 5;
  int n  = g * 512 + nt * 16 + (lane & 15);
  int k0 = kk * 32 + (lane >> 4) * 8;
  const float* src = Whh + ((size_t)l * 1536 + n) * 512 + k0;
  unsigned short t[8];
#pragma unroll
  for (int j = 0; j < 8; ++j) t[j] = f2bf(src[j]);
  uint4 v;
  v.x = t[0] | ((unsigned)t[1] << 16);
  v.y = t[2] | ((unsigned)t[3] << 16);
  v.z = t[4] | ((unsigned)t[5] << 16);
  v.w = t[6] | ((unsigned)t[7] << 16);
  *(uint4*)(Wp + (size_t)gid * 8) = v;
}

// Pack Wih [3][1536][8] -> zero-padded (K=8 of 32) B-fragments, gate-interleaved:
// dst chunk gid = ((l*32+nt)*3+g)*64+lane
__global__ void prep_wih(const float* __restrict__ Wih, unsigned short* __restrict__ Wip){
  int gid = blockIdx.x * 256 + threadIdx.x;     // 18432 total
  int lane = gid & 63;
  int r = gid >> 6;
  int g  = r % 3;  r /= 3;
  int nt = r & 31;
  int l  = r >> 5;
  unsigned short t[8] = {0,0,0,0,0,0,0,0};
  if ((lane >> 4) == 0){
    int n = g * 512 + nt * 16 + (lane & 15);
    const float* src = Wih + ((size_t)l * 1536 + n) * 8;
#pragma unroll
    for (int j = 0; j < 8; ++j) t[j] = f2bf(src[j]);
  }
  uint4 v;
  v.x = t[0] | ((unsigned)t[1] << 16);
  v.y = t[2] | ((unsigned)t[3] << 16);
  v.z = t[4] | ((unsigned)t[5] << 16);
  v.w = t[6] | ((unsigned)t[7] << 16);
  *(uint4*)(Wip + (size_t)gid * 8) = v;
}

// Main: 256 blocks x 1024 threads (16 waves), 1 block/CU (LDS-padded to force it).
// Pair (bid, bid^4) shares batch rows [b0,b0+32); each computes 256 of 512 cols.
// Weight latency hidden by a 3-slot NAMED-REGISTER pipeline (9 short8 in flight/wave);
// loads for the partner-half kk are issued before the mid-barrier (stay in flight across).
__global__ __launch_bounds__(1024, 4) void gru_main(
    const float* __restrict__ x,
    const unsigned short* __restrict__ Wp,
    const unsigned short* __restrict__ Wip,
    const float* __restrict__ bih,
    const float* __restrict__ bhh,
    float* __restrict__ out,
    int* __restrict__ flags,
    unsigned int* __restrict__ xchg)
{
  __shared__ __align__(16) unsigned short hB[2][32 * HSTR];  // 68,608 B
  __shared__ __align__(16) unsigned short xpack[2][1024];    //  4,096 B
  __shared__ unsigned short hpad[8192];                      // 16,384 B: forces 1 block/CU

  const int tid  = threadIdx.x;
  const int wv   = tid >> 6;
  const int lane = tid & 63;
  const int l15  = lane & 15;
  const int l4   = lane >> 4;
  if (tid == 1023) hpad[0] = 0;   // keep pad allocated

  const int bid     = blockIdx.x;
  const int bgroup  = ((bid >> 3) << 2) | (bid & 3);   // [0,128)
  const int half    = (bid >> 2) & 1;
  const int partner = bid ^ 4;
  const int b0      = bgroup * 32;
  const int col     = half * 256 + wv * 16 + l15;      // global col
  const int ntc     = half * 16 + wv;                  // global 16-col tile index
  const int pcb0    = (1 - half) * 256;                // partner's column base
  const int ko0     = half * 8;                        // own-half kk start
  const int pk0     = 8 - ko0;                         // partner-half kk start
#define KK(i) ((i) < 8 ? (ko0 + (i)) : (pk0 + (i) - 8))

  unsigned int* xown = xchg + (size_t)bid * 8192;      // 2 slots x 4096 u32
  const unsigned int* xpbase = xchg + (size_t)partner * 8192 + tid;

  // hoisted per-thread constants
  const int dR   = tid >> 7;                           // partner-copy row base (0..7)
  const int dC   = tid & 127;                          // partner-copy colpair
  const int dOff = dR * HSTR + pcb0 + dC * 2;          // + e*8*HSTR, shorts
  const int sOff = l4 * 512 + wv * 8 + (l15 >> 1);     // mailbox store base (+m*2048+q*128)
  const int hOff = l4 * 4 * HSTR + col;                // LDS h write base (+ (m*16+q)*HSTR)

  for (int i = tid; i < 32 * HSTR; i += 1024){ hB[0][i] = 0; }

  float hreg[2][4];
#pragma unroll
  for (int m = 0; m < 2; ++m)
#pragma unroll
    for (int q = 0; q < 4; ++q) hreg[m][q] = 0.f;

  // xpack writer mapping: tid = (m*64+lane)*8 + j
  const int xl = (tid >> 3) & 63;
  const size_t xbase = ((size_t)(b0 + (tid >> 9) * 16 + (xl & 15))) * (S_LEN * IN_D) + (tid & 7);
  const int xvalid = (xl < 16);
  { float xv = xvalid ? x[xbase] : 0.f; xpack[0][tid] = f2bf(xv); }
  __syncthreads();

  const int aoff0 = l15 * HSTR + l4 * 8;          // A-frag m=0, shorts
  const int aoff1 = aoff0 + 16 * HSTR;            // A-frag m=1

  const unsigned short* wklB = Wp  + (size_t)ntc * 48 * 512 + (size_t)lane * 8;
  const unsigned short* wilB = Wip + (size_t)ntc * 3  * 512 + (size_t)lane * 8;

#define WLOAD(sl, i) { const unsigned short* w_ = wkl + KK(i) * 1536; \
    sR##sl = *(const short8*)(w_); \
    sZ##sl = *(const short8*)(w_ + 512); \
    sN##sl = *(const short8*)(w_ + 1024); }
#define WCONS(sl, i) { \
    short8 a0 = *(const short8*)(hbc + aoff0 + KK(i) * 32); \
    short8 a1 = *(const short8*)(hbc + aoff1 + KK(i) * 32); \
    accR0 = MFMA(a0, sR##sl, accR0);  accR1 = MFMA(a1, sR##sl, accR1); \
    accZ0 = MFMA(a0, sZ##sl, accZ0);  accZ1 = MFMA(a1, sZ##sl, accZ1); \
    accN0 = MFMA(a0, sN##sl, accN0);  accN1 = MFMA(a1, sN##sl, accN1); }

  int cur = 0;
#pragma unroll 1
  for (int t = 0; t < S_LEN; ++t){
    const unsigned short* xp = &xpack[t & 1][0];
#pragma unroll
    for (int l = 0; l < NL; ++l){
      const int s    = t * NL + l;
      const int last = (s == S_LEN * NL - 1);
      const unsigned short* hbc = hB[cur];
      unsigned short*       hbw = hB[cur];
      unsigned short*       hbn = hB[cur ^ 1];
      const unsigned short* wkl = wklB + (size_t)l * (32 * 48 * 512);
      const unsigned short* wil = wilB + (size_t)l * (32 * 3 * 512);

      short8 sR0,sZ0,sN0, sR1,sZ1,sN1, sR2,sZ2,sN2;

      // issue gi weight loads + biases + prime the 3-slot pipeline (all L2, independent)
      short8 iR = *(const short8*)(wil);
      short8 iZ = *(const short8*)(wil + 512);
      short8 iN = *(const short8*)(wil + 1024);
      const float vR  = bih[l * 1536 + col]       + bhh[l * 1536 + col];
      const float vZ  = bih[l * 1536 + 512 + col] + bhh[l * 1536 + 512 + col];
      const float vNi = bih[l * 1536 + 1024 + col];
      const float vNh = bhh[l * 1536 + 1024 + col];
      WLOAD(0, 0)  WLOAD(1, 1)  WLOAD(2, 2)

      // poll partner + issue the 4 mailbox loads (UC); LDS writes deferred to mid-barrier
      unsigned c0, c1, c2, c3;
      if (s > 0){
        while (__hip_atomic_load(&flags[partner], __ATOMIC_RELAXED, __HIP_MEMORY_SCOPE_AGENT) < s)
          __builtin_amdgcn_s_sleep(4);
        const unsigned int* src = xpbase + ((s - 1) & 1) * 4096;
        c0 = __hip_atomic_load(src,        __ATOMIC_RELAXED, __HIP_MEMORY_SCOPE_AGENT);
        c1 = __hip_atomic_load(src + 1024, __ATOMIC_RELAXED, __HIP_MEMORY_SCOPE_AGENT);
        c2 = __hip_atomic_load(src + 2048, __ATOMIC_RELAXED, __HIP_MEMORY_SCOPE_AGENT);
        c3 = __hip_atomic_load(src + 3072, __ATOMIC_RELAXED, __HIP_MEMORY_SCOPE_AGENT);
      }

      f32x4 accR0 = {vR,vR,vR,vR},     accR1 = {vR,vR,vR,vR};
      f32x4 accZ0 = {vZ,vZ,vZ,vZ},     accZ1 = {vZ,vZ,vZ,vZ};
      f32x4 accN0 = {vNh,vNh,vNh,vNh}, accN1 = {vNh,vNh,vNh,vNh};
      f32x4 giN0  = {vNi,vNi,vNi,vNi}, giN1  = {vNi,vNi,vNi,vNi};

      // gi = x_t @ Wih^T
      {
        short8 ax0 = *(const short8*)(xp + lane * 8);
        short8 ax1 = *(const short8*)(xp + 512 + lane * 8);
        accR0 = MFMA(ax0, iR, accR0);  accR1 = MFMA(ax1, iR, accR1);
        accZ0 = MFMA(ax0, iZ, accZ0);  accZ1 = MFMA(ax1, iZ, accZ1);
        giN0  = MFMA(ax0, iN, giN0);   giN1  = MFMA(ax1, iN, giN1);
      }

      // own-half kk: consume seq[i], reload slot with seq[i+3]
      WCONS(0, 0)  WLOAD(0, 3)
      WCONS(1, 1)  WLOAD(1, 4)
      WCONS(2, 2)  WLOAD(2, 5)
      WCONS(0, 3)  WLOAD(0, 6)
      WCONS(1, 4)  WLOAD(1, 7)
      WCONS(2, 5)  WLOAD(2, 8)
      WCONS(0, 6)  WLOAD(0, 9)
      WCONS(1, 7)  WLOAD(1, 10)

      // partner-copy LDS writes (compiler waits only on c0..c3; weight loads stay in flight)
      if (s > 0){
        *(unsigned*)(hbw + dOff)            = c0;
        *(unsigned*)(hbw + dOff + 8 * HSTR)  = c1;
        *(unsigned*)(hbw + dOff + 16 * HSTR) = c2;
        *(unsigned*)(hbw + dOff + 24 * HSTR) = c3;
      }
      __syncthreads();   // partner half of hB[cur] complete

      // partner-half kk
      WCONS(2, 8)   WLOAD(2, 11)
      WCONS(0, 9)   WLOAD(0, 12)
      WCONS(1, 10)  WLOAD(1, 13)
      WCONS(2, 11)  WLOAD(2, 14)
      WCONS(0, 12)  WLOAD(0, 15)
      WCONS(1, 13)
      WCONS(2, 14)
      WCONS(0, 15)

      // gates; write own half to hB[cur^1] + mailbox slot s&1
      unsigned int* xob = xown + (s & 1) * 4096;
#pragma unroll
      for (int m = 0; m < 2; ++m){
        f32x4 aR  = m ? accR1 : accR0;
        f32x4 aZ  = m ? accZ1 : accZ0;
        f32x4 aN4 = m ? accN1 : accN0;
        f32x4 gN  = m ? giN1  : giN0;
#pragma unroll
        for (int q = 0; q < 4; ++q){
          float r  = 1.f / (1.f + __expf(-aR[q]));
          float z  = 1.f / (1.f + __expf(-aZ[q]));
          float aN = gN[q] + r * aN4[q];
          float n  = 1.f - 2.f / (1.f + __expf(2.f * aN));
          float hn = n + z * (hreg[m][q] - n);   // (1-z)*n + z*h
          hreg[m][q] = hn;
          unsigned bf = f2bf(hn);
          unsigned pb = (unsigned)__shfl_xor((int)bf, 1);
          if (!(l15 & 1)){
            unsigned pk = bf | (pb << 16);
            *(unsigned*)(hbn + hOff + (m * 16 + q) * HSTR) = pk;
            if (!last)
              __hip_atomic_store(xob + sOff + m * 2048 + q * 128, pk,
                                 __ATOMIC_RELAXED, __HIP_MEMORY_SCOPE_AGENT);
          }
        }
      }

      // stage x(t+1) before the end-of-step barrier
      if (l == NL - 1 && t < S_LEN - 1){
        float xv = xvalid ? x[xbase + (size_t)(t + 1) * IN_D] : 0.f;
        xpack[(t + 1) & 1][tid] = f2bf(xv);
      }

      if (!last){
        asm volatile("s_waitcnt vmcnt(0)" ::: "memory");   // mailbox stores drained
        __syncthreads();
        if (tid == 0)
          __hip_atomic_store(&flags[bid], s + 1, __ATOMIC_RELAXED, __HIP_MEMORY_SCOPE_AGENT);
      }
      cur ^= 1;
    }
  }
#undef WLOAD
#undef WCONS
#undef KK

  // epilogue: own 32r x 16c slice from registers
#pragma unroll
  for (int m = 0; m < 2; ++m)
#pragma unroll
    for (int q = 0; q < 4; ++q){
      int b = m * 16 + l4 * 4 + q;
      out[((size_t)(b0 + b)) * 512 + col] = hreg[m][q];
    }
}

extern "C" void kernel_launch(void* const* d_in, const int* in_sizes, int n_in,
                              void* d_out, int out_size, void* d_ws, size_t ws_size,
                              hipStream_t stream){
  const float* x   = (const float*)d_in[0];
  const float* Wih = (const float*)d_in[1];
  const float* Whh = (const float*)d_in[2];
  const float* bih = (const float*)d_in[3];
  const float* bhh = (const float*)d_in[4];

  unsigned char* ws = (unsigned char*)d_ws;
  unsigned short* Wp   = (unsigned short*)(ws + OFF_WHH);
  unsigned short* Wip  = (unsigned short*)(ws + OFF_WIH);
  int*            flg  = (int*)(ws + OFF_FLAG);
  unsigned int*   xchg = (unsigned int*)(ws + OFF_XCHG);

  hipMemsetAsync(flg, 0, 256 * sizeof(int), stream);   // generation flags start at 0 every call
  prep_whh <<<1152, 256, 0, stream>>>(Whh, Wp);
  prep_wih <<<  72, 256, 0, stream>>>(Wih, Wip);
  gru_main <<< 256, 1024, 0, stream>>>(x, Wp, Wip, bih, bhh, (float*)d_out, flg, xchg);
}

// Round 9
// 3720.828 us; speedup vs baseline: 3.4912x; 3.4912x over previous
//
#include <hip/hip_runtime.h>

typedef __attribute__((ext_vector_type(8))) short short8;
typedef __attribute__((ext_vector_type(4))) float f32x4;
typedef __attribute__((ext_vector_type(4))) int   i32x4;

#define MFMA(a,b,c)  __builtin_amdgcn_mfma_f32_16x16x32_bf16(a,b,c,0,0,0)
#define MFMAI(a,b,c) __builtin_amdgcn_mfma_i32_16x16x64_i8(a,b,c,0,0,0)

// Problem dims
#define S_LEN 128
#define IN_D  8
#define HID   512
#define NL    3
#define H8STR 528       // i8 h row stride (bytes): 512 + 16 pad, 16B aligned

// ws layout (bytes)
#define OFF_WI8  0                       // [3][32nt][8kk][3g][64][16B] i8 = 2,359,296
#define OFF_WIH  (2359296)               // [3][32][3][64][8] bf16        =   294,912
#define OFF_SW   (2359296 + 294912)      // 4608 f32 dequant scales       =    18,432
#define OFF_SWI  (OFF_SW + 18432)        // 4608 f32 inv scales           =    18,432
#define OFF_FLAG (OFF_SWI + 18432)       // 256 int                       =     1,024
#define OFF_XCHG (OFF_FLAG + 1024)       // 256 blk * 2 slot * 8 KB       = 4,194,304

__device__ __forceinline__ unsigned short f2bf(float f){
  unsigned u = __float_as_uint(f);
  u += 0x7FFFu + ((u >> 16) & 1u);
  return (unsigned short)(u >> 16);
}

// Per-row absmax scales for Whh: row = l*1536 + g*512 + col (4608 rows x 512)
__global__ void prep_scale(const float* __restrict__ Whh,
                           float* __restrict__ sw, float* __restrict__ swi){
  int row = blockIdx.x * 4 + (threadIdx.x >> 6);
  int lane = threadIdx.x & 63;
  const float* src = Whh + (size_t)row * 512;
  float m = 0.f;
#pragma unroll
  for (int i = 0; i < 8; ++i) m = fmaxf(m, fabsf(src[lane + i * 64]));
#pragma unroll
  for (int off = 32; off; off >>= 1) m = fmaxf(m, (float)__shfl_xor(m, off));
  m = fmaxf(m, 1e-20f);
  if (lane == 0){ sw[row] = m / 127.f; swi[row] = 127.f / m; }
}

// Quantize+pack Whh -> i8 B-fragments (K=64), gate-interleaved per kk:
// chunk gid = (((l*32+nt)*8+kk)*3+g)*64+lane, 16 bytes: byte j =
//   q(Whh[l][g*512+nt*16+(lane&15)][kk*64+(lane>>4)*16+j])
__global__ void prep_wi8(const float* __restrict__ Whh, const float* __restrict__ swi,
                         unsigned char* __restrict__ Wp8){
  int gid = blockIdx.x * 256 + threadIdx.x;     // 147456 total
  int lane = gid & 63;
  int r = gid >> 6;
  int g  = r % 3;  r /= 3;
  int kk = r & 7;  r >>= 3;
  int nt = r & 31;
  int l  = r >> 5;
  int row = l * 1536 + g * 512 + nt * 16 + (lane & 15);
  int k0  = kk * 64 + (lane >> 4) * 16;
  const float* src = Whh + (size_t)row * 512 + k0;
  float si = swi[row];
  uint4 v = {0,0,0,0};
  unsigned w[4] = {0,0,0,0};
#pragma unroll
  for (int j = 0; j < 16; ++j){
    int q = (int)rintf(src[j] * si);
    q = q > 127 ? 127 : (q < -127 ? -127 : q);
    w[j >> 2] |= ((unsigned)(q & 0xFF)) << ((j & 3) * 8);
  }
  v.x = w[0]; v.y = w[1]; v.z = w[2]; v.w = w[3];
  *(uint4*)(Wp8 + (size_t)gid * 16) = v;
}

// Pack Wih [3][1536][8] -> zero-padded (K=8 of 32) bf16 B-fragments, gate-interleaved
__global__ void prep_wih(const float* __restrict__ Wih, unsigned short* __restrict__ Wip){
  int gid = blockIdx.x * 256 + threadIdx.x;     // 18432 total
  int lane = gid & 63;
  int r = gid >> 6;
  int g  = r % 3;  r /= 3;
  int nt = r & 31;
  int l  = r >> 5;
  unsigned short t[8] = {0,0,0,0,0,0,0,0};
  if ((lane >> 4) == 0){
    int n = g * 512 + nt * 16 + (lane & 15);
    const float* src = Wih + ((size_t)l * 1536 + n) * 8;
#pragma unroll
    for (int j = 0; j < 8; ++j) t[j] = f2bf(src[j]);
  }
  uint4 v;
  v.x = t[0] | ((unsigned)t[1] << 16);
  v.y = t[2] | ((unsigned)t[3] << 16);
  v.z = t[4] | ((unsigned)t[5] << 16);
  v.w = t[6] | ((unsigned)t[7] << 16);
  *(uint4*)(Wip + (size_t)gid * 8) = v;
}

// Main: 256 blocks x 1024 threads (16 waves), 1 block/CU (LDS 85KB, genuinely used).
// Pair (bid, bid^4) shares batch rows [b0,b0+32); each computes 256 of 512 cols.
// Whh stream + h + MFMA all int8 (K=64): per-CU weight stream 384 KB/step.
// h fp32 master in registers; h i8 double-buffered in LDS; gi stays bf16 MFMA.
__global__ __launch_bounds__(1024) void gru_main(
    const float* __restrict__ x,
    const unsigned char* __restrict__ Wp8,
    const unsigned short* __restrict__ Wip,
    const float* __restrict__ bih,
    const float* __restrict__ bhh,
    const float* __restrict__ sw,
    float* __restrict__ out,
    int* __restrict__ flags,
    unsigned int* __restrict__ xchg)
{
  __shared__ __align__(16) unsigned char  hB8[2][32 * H8STR]; // 33,792 B
  __shared__ __align__(16) unsigned short xpack[2][1024];     //  4,096 B
  __shared__ float sBrz[3 * 1024];                            // 12,288 B
  __shared__ float sBni[3 * 512];                             //  6,144 B
  __shared__ float sBnh[3 * 512];                             //  6,144 B
  __shared__ float sSw[4608];                                 // 18,432 B
  __shared__ int   pad[1024];                                 //  4,096 B -> total 84,992 (1 blk/CU)

  const int tid  = threadIdx.x;
  const int wv   = tid >> 6;
  const int lane = tid & 63;
  const int l15  = lane & 15;
  const int l4   = lane >> 4;

  const int bid     = blockIdx.x;
  const int bgroup  = ((bid >> 3) << 2) | (bid & 3);   // [0,128)
  const int half    = (bid >> 2) & 1;
  const int partner = bid ^ 4;
  const int b0      = bgroup * 32;
  const int col     = half * 256 + wv * 16 + l15;      // global col
  const int ntc     = half * 16 + wv;                  // 16-col tile index
  const int pcb0    = (1 - half) * 256;                // partner col base (bytes in i8 row)
  const int ko0     = half * 4;                        // own-half kk start (kk of 64)
  const int pk0     = 4 - ko0;                         // partner-half kk start

  // pad liveness guard (flags never negative) — prevents LDS DCE (R8 lesson)
  if (flags[bid] == -1) pad[tid] = tid;

  unsigned int* xown = xchg + (size_t)bid * 4096;      // 2 slots x 2048 u32
  const unsigned int* xpb = xchg + (size_t)partner * 4096 + tid;
  const int dOff = (tid >> 6) * H8STR + pcb0 + (tid & 63) * 4;   // partner-copy dest (byte)

  for (int i = tid; i < 2 * 32 * H8STR / 4; i += 1024) ((unsigned*)hB8)[i] = 0;
  for (int i = tid; i < 3072; i += 1024){
    int l = i >> 10, c = i & 1023;
    sBrz[i] = bih[l * 1536 + c] + bhh[l * 1536 + c];
  }
  for (int i = tid; i < 1536; i += 1024){
    int l = i >> 9, c = i & 511;
    sBni[i] = bih[l * 1536 + 1024 + c];
    sBnh[i] = bhh[l * 1536 + 1024 + c];
  }
  for (int i = tid; i < 4608; i += 1024) sSw[i] = sw[i];

  float hreg[2][4];
#pragma unroll
  for (int m = 0; m < 2; ++m)
#pragma unroll
    for (int q = 0; q < 4; ++q) hreg[m][q] = 0.f;

  // xpack writer: tid = (m*64+lane)*8 + j
  const int xl = (tid >> 3) & 63;
  const size_t xbase = ((size_t)(b0 + (tid >> 9) * 16 + (xl & 15))) * (S_LEN * IN_D) + (tid & 7);
  const int xvalid = (xl < 16);
  { float xv = xvalid ? x[xbase] : 0.f; xpack[0][tid] = f2bf(xv); }
  __syncthreads();

  const int aoff0 = l15 * H8STR + l4 * 16;        // A-frag m=0 (rows 0..15), bytes
  const int aoff1 = aoff0 + 16 * H8STR;           // A-frag m=1

  const unsigned char*  wklB = Wp8 + (size_t)ntc * (8 * 3 * 64 * 16) + (size_t)lane * 16;
  const unsigned short* wilB = Wip + (size_t)ntc * 3 * 512 + (size_t)lane * 8;
  const float i127 = 1.f / 127.f;

#define DO_KK(kkv) { \
    const int kk_ = (kkv); \
    const unsigned char* w_ = wkl + kk_ * 3072; \
    i32x4 bR = *(const i32x4*)(w_); \
    i32x4 bZ = *(const i32x4*)(w_ + 1024); \
    i32x4 bN = *(const i32x4*)(w_ + 2048); \
    i32x4 a0 = *(const i32x4*)(hb8c + aoff0 + kk_ * 64); \
    i32x4 a1 = *(const i32x4*)(hb8c + aoff1 + kk_ * 64); \
    accR0 = MFMAI(a0, bR, accR0);  accR1 = MFMAI(a1, bR, accR1); \
    accZ0 = MFMAI(a0, bZ, accZ0);  accZ1 = MFMAI(a1, bZ, accZ1); \
    accN0 = MFMAI(a0, bN, accN0);  accN1 = MFMAI(a1, bN, accN1); \
  }

  int cur = 0;
#pragma unroll 1
  for (int t = 0; t < S_LEN; ++t){
    const unsigned short* xp = &xpack[t & 1][0];
#pragma unroll 1
    for (int l = 0; l < NL; ++l){
      const int s    = t * NL + l;
      const int last = (s == S_LEN * NL - 1);
      const unsigned char* hb8c = hB8[cur];
      unsigned char*       hb8w = hB8[cur];      // partner-copy dest (disjoint half)
      unsigned char*       hb8n = hB8[cur ^ 1];
      const unsigned char*  wkl = wklB + (size_t)l * (32 * 8 * 3 * 64 * 16);
      const unsigned short* wil = wilB + (size_t)l * (32 * 3 * 512);

      // poll partner + issue the 2 mailbox u32 loads; LDS writes deferred to mid-barrier
      unsigned c0 = 0, c1 = 0;
      if (s > 0){
        while (__hip_atomic_load(&flags[partner], __ATOMIC_RELAXED, __HIP_MEMORY_SCOPE_AGENT) < s)
          __builtin_amdgcn_s_sleep(4);
        const unsigned int* src = xpb + ((s - 1) & 1) * 2048;
        c0 = __hip_atomic_load(src,        __ATOMIC_RELAXED, __HIP_MEMORY_SCOPE_AGENT);
        c1 = __hip_atomic_load(src + 1024, __ATOMIC_RELAXED, __HIP_MEMORY_SCOPE_AGENT);
      }

      // gi accumulators (carry biases) + gi = x_t @ Wih^T (bf16, K=8 of 32)
      const float vR  = sBrz[l * 1024 + col];
      const float vZ  = sBrz[l * 1024 + 512 + col];
      const float vNi = sBni[l * 512 + col];
      const float vNh = sBnh[l * 512 + col];
      f32x4 giR0 = {vR,vR,vR,vR},     giR1 = {vR,vR,vR,vR};
      f32x4 giZ0 = {vZ,vZ,vZ,vZ},     giZ1 = {vZ,vZ,vZ,vZ};
      f32x4 giN0 = {vNi,vNi,vNi,vNi}, giN1 = {vNi,vNi,vNi,vNi};
      {
        short8 ax0 = *(const short8*)(xp + lane * 8);
        short8 ax1 = *(const short8*)(xp + 512 + lane * 8);
        short8 iR = *(const short8*)(wil);
        short8 iZ = *(const short8*)(wil + 512);
        short8 iN = *(const short8*)(wil + 1024);
        giR0 = MFMA(ax0, iR, giR0);  giR1 = MFMA(ax1, iR, giR1);
        giZ0 = MFMA(ax0, iZ, giZ0);  giZ1 = MFMA(ax1, iZ, giZ1);
        giN0 = MFMA(ax0, iN, giN0);  giN1 = MFMA(ax1, iN, giN1);
      }

      i32x4 accR0 = {0,0,0,0}, accR1 = {0,0,0,0};
      i32x4 accZ0 = {0,0,0,0}, accZ1 = {0,0,0,0};
      i32x4 accN0 = {0,0,0,0}, accN1 = {0,0,0,0};

      // own-half kks (h cols this block wrote last step)
#pragma unroll
      for (int kx = 0; kx < 4; ++kx) DO_KK(ko0 + kx);

      // partner-copy LDS writes + mid-barrier
      if (s > 0){
        *(unsigned*)(hb8w + dOff)             = c0;
        *(unsigned*)(hb8w + dOff + 16 * H8STR) = c1;
      }
      __syncthreads();

      // partner-half kks
#pragma unroll
      for (int kx = 0; kx < 4; ++kx) DO_KK(pk0 + kx);

      // gates: dequant i32 accs, fp32 nonlinearity, h write i8 (LDS + mailbox)
      const float kR = sSw[l * 1536 + col] * i127;
      const float kZ = sSw[l * 1536 + 512 + col] * i127;
      const float kN = sSw[l * 1536 + 1024 + col] * i127;
      unsigned int* xob = xown + (s & 1) * 2048;
#pragma unroll
      for (int m = 0; m < 2; ++m){
        i32x4 aR = m ? accR1 : accR0;
        i32x4 aZ = m ? accZ1 : accZ0;
        i32x4 aN = m ? accN1 : accN0;
        f32x4 gR = m ? giR1 : giR0;
        f32x4 gZ = m ? giZ1 : giZ0;
        f32x4 gN = m ? giN1 : giN0;
#pragma unroll
        for (int q = 0; q < 4; ++q){
          int b = m * 16 + l4 * 4 + q;
          float rpre = gR[q] + (float)aR[q] * kR;
          float zpre = gZ[q] + (float)aZ[q] * kZ;
          float r  = 1.f / (1.f + __expf(-rpre));
          float z  = 1.f / (1.f + __expf(-zpre));
          float an = gN[q] + r * ((float)aN[q] * kN + vNh);
          float n  = 1.f - 2.f / (1.f + __expf(2.f * an));
          float hn = n + z * (hreg[m][q] - n);
          hreg[m][q] = hn;
          int hq = (int)rintf(hn * 127.f);
          unsigned b8  = (unsigned)(hq & 0xFF);
          unsigned p1  = (unsigned)__shfl_xor((int)b8, 1);
          unsigned h16 = b8 | (p1 << 8);
          unsigned p2  = (unsigned)__shfl_xor((int)h16, 2);
          unsigned w32 = (h16 & 0xFFFF) | (p2 << 16);
          if (!(l15 & 3)){
            *(unsigned*)(hb8n + b * H8STR + col) = w32;
            if (!last)
              __hip_atomic_store(xob + b * 64 + wv * 4 + (l15 >> 2), w32,
                                 __ATOMIC_RELAXED, __HIP_MEMORY_SCOPE_AGENT);
          }
        }
      }

      // stage x(t+1) before the end-of-step barrier
      if (l == NL - 1 && t < S_LEN - 1){
        float xv = xvalid ? x[xbase + (size_t)(t + 1) * IN_D] : 0.f;
        xpack[(t + 1) & 1][tid] = f2bf(xv);
      }

      if (!last){
        asm volatile("s_waitcnt vmcnt(0)" ::: "memory");   // mailbox stores drained
        __syncthreads();
        if (tid == 0)
          __hip_atomic_store(&flags[bid], s + 1, __ATOMIC_RELAXED, __HIP_MEMORY_SCOPE_AGENT);
      }
      cur ^= 1;
    }
  }
#undef DO_KK

  // epilogue: own 32r x 16c slice from fp32 registers
#pragma unroll
  for (int m = 0; m < 2; ++m)
#pragma unroll
    for (int q = 0; q < 4; ++q){
      int b = m * 16 + l4 * 4 + q;
      out[((size_t)(b0 + b)) * 512 + col] = hreg[m][q];
    }

  if (flags[bid] == -2) out[0] = (float)pad[tid];   // pad liveness (never true)
}

extern "C" void kernel_launch(void* const* d_in, const int* in_sizes, int n_in,
                              void* d_out, int out_size, void* d_ws, size_t ws_size,
                              hipStream_t stream){
  const float* x   = (const float*)d_in[0];
  const float* Wih = (const float*)d_in[1];
  const float* Whh = (const float*)d_in[2];
  const float* bih = (const float*)d_in[3];
  const float* bhh = (const float*)d_in[4];

  unsigned char* ws = (unsigned char*)d_ws;
  unsigned char*  Wp8  = (unsigned char*)(ws + OFF_WI8);
  unsigned short* Wip  = (unsigned short*)(ws + OFF_WIH);
  float*          sw   = (float*)(ws + OFF_SW);
  float*          swi  = (float*)(ws + OFF_SWI);
  int*            flg  = (int*)(ws + OFF_FLAG);
  unsigned int*   xchg = (unsigned int*)(ws + OFF_XCHG);

  hipMemsetAsync(flg, 0, 256 * sizeof(int), stream);
  prep_scale<<<1152, 256, 0, stream>>>(Whh, sw, swi);
  prep_wi8  <<< 576, 256, 0, stream>>>(Whh, swi, Wp8);
  prep_wih  <<<  72, 256, 0, stream>>>(Wih, Wip);
  gru_main  <<< 256, 1024, 0, stream>>>(x, Wp8, Wip, bih, bhh, sw, (float*)d_out, flg, xchg);
}